// Round 7
// baseline (193.001 us; speedup 1.0000x reference)
//
#include <hip/hip_runtime.h>
#include <hip/hip_bf16.h>
#include <math.h>

#define BATCH 16
#define SEQ   2048
#define HID   128
#define DIM   64

#define KCOLS 32                      // k-columns per attention block
#define NKBLK (SEQ / KCOLS)           // 64 k-blocks per batch
#define CACHE_STRIDE 136              // 128B cache/lane + 8B pad (bank spread)
#define CACHE_BYTES  (1024 * CACHE_STRIDE)

typedef __attribute__((ext_vector_type(8))) short bf16x8;
typedef __attribute__((ext_vector_type(4))) float f32x4;

// 0.125 (1/sqrt(D)) * log2(e): folded into Wq so MFMA emits log2-domain scores
#define QSCALE 0.18033688011112042f
#define C0_PE  0.07195578314043169f   // ln(10000)/128

static __device__ __forceinline__ ushort f2bf(float f) {
    __hip_bfloat16 h = __float2bfloat16(f);
    return *reinterpret_cast<ushort*>(&h);
}

static __device__ __forceinline__ float fast_exp2(float x) {
#if __has_builtin(__builtin_amdgcn_exp2f)
    return __builtin_amdgcn_exp2f(x);
#else
    return exp2f(x);
#endif
}

static __device__ __forceinline__ unsigned packf16(float a, float b) {
    _Float16 ha = (_Float16)a, hb = (_Float16)b;
    unsigned short ua = __builtin_bit_cast(unsigned short, ha);
    unsigned short ub = __builtin_bit_cast(unsigned short, hb);
    return ((unsigned)ub << 16) | ua;
}

static __device__ __forceinline__ float2 unpackf16(unsigned u) {
    _Float16 lo = __builtin_bit_cast(_Float16, (unsigned short)(u & 0xffffu));
    _Float16 hi = __builtin_bit_cast(_Float16, (unsigned short)(u >> 16));
    return make_float2((float)lo, (float)hi);
}

// ---------------------------------------------------------------------------
// Prep (1024 blocks): wvf[h] = Wv[h,:]·Wf ;  Wt = bf16 [Wq*QSCALE | Wk]^T ;
// pe[s][h] = sinusoidal PE table (f32, 1 MB).
// ---------------------------------------------------------------------------
__global__ __launch_bounds__(256) void k_prep(
    const float* __restrict__ Wq, const float* __restrict__ Wk,
    const float* __restrict__ Wv, const float* __restrict__ Wf,
    ushort* __restrict__ Wt, float* __restrict__ wvf, float* __restrict__ pe) {
    const int gid = blockIdx.x * 256 + threadIdx.x;
    if (gid < HID) {
        float s = 0.f;
        #pragma unroll 8
        for (int d = 0; d < DIM; ++d) s += Wv[gid * DIM + d] * Wf[d];
        wvf[gid] = s;
    }
    if (gid < 128 * 128) {
        int col = gid >> 7, k = gid & 127;
        float v = (col < 64) ? Wq[k * DIM + col] * QSCALE : Wk[k * DIM + (col - 64)];
        Wt[gid] = f2bf(v);
    }
    {
        int s = gid >> 7, h = gid & 127;
        int he = h & ~1;
        float ang = (float)s * __expf(-(float)he * C0_PE);
        pe[gid] = (h & 1) ? __cosf(ang) : __sinf(ang);
    }
}

// ---------------------------------------------------------------------------
// QKV (MFMA, no LDS): block = 64 rows, wave = 16 rows.
// ---------------------------------------------------------------------------
__global__ __launch_bounds__(256) void k_qkv(
    const float* __restrict__ x, const ushort* __restrict__ Wt,
    const float* __restrict__ wvf, const float* __restrict__ pe,
    ushort* __restrict__ Qb, ushort* __restrict__ Kb, float* __restrict__ vf)
{
    const int tid  = threadIdx.x;
    const int wave = tid >> 6;
    const int lane = tid & 63;
    const int quad = lane >> 4;
    const int col  = lane & 15;
    const int rowbase = blockIdx.x * 64 + wave * 16;
    const int grow = rowbase + col;
    const int srow = grow & (SEQ - 1);

    bf16x8 af[4];
    float vpart = 0.f;
    #pragma unroll
    for (int c = 0; c < 4; ++c) {
        const float* xp = x + (size_t)grow * HID + quad * 8 + c * 32;
        float4 v0 = *(const float4*)(xp);
        float4 v1 = *(const float4*)(xp + 4);
        const float* per = pe + (size_t)srow * HID + quad * 8 + c * 32;
        float4 p0 = *(const float4*)(per);
        float4 p1 = *(const float4*)(per + 4);
        float t[8] = {v0.x + p0.x, v0.y + p0.y, v0.z + p0.z, v0.w + p0.w,
                      v1.x + p1.x, v1.y + p1.y, v1.z + p1.z, v1.w + p1.w};
        const float* wp = wvf + quad * 8 + c * 32;
        float4 w0 = *(const float4*)(wp);
        float4 w1 = *(const float4*)(wp + 4);
        vpart += t[0] * w0.x + t[1] * w0.y + t[2] * w0.z + t[3] * w0.w +
                 t[4] * w1.x + t[5] * w1.y + t[6] * w1.z + t[7] * w1.w;
        short* ap = (short*)&af[c];
        #pragma unroll
        for (int j = 0; j < 8; ++j) ap[j] = (short)f2bf(t[j]);
    }

    vpart += __shfl_xor(vpart, 16);
    vpart += __shfl_xor(vpart, 32);
    if (quad == 0) vf[grow] = vpart;

    #pragma unroll
    for (int t = 0; t < 8; ++t) {
        const ushort* wrow = Wt + (size_t)(t * 16 + col) * 128 + quad * 8;
        f32x4 acc = {0.f, 0.f, 0.f, 0.f};
        #pragma unroll
        for (int c = 0; c < 4; ++c) {
            bf16x8 bfr = *(const bf16x8*)(wrow + c * 32);
            acc = __builtin_amdgcn_mfma_f32_16x16x32_bf16(af[c], bfr, acc, 0, 0, 0);
        }
        const int cb = (t & 3) * 16 + col;
        ushort* dst = (t < 4) ? Qb : Kb;
        const int r0 = rowbase + quad * 4;
        #pragma unroll
        for (int r = 0; r < 4; ++r)
            dst[(size_t)(r0 + r) * DIM + cb] = f2bf(acc[r]);
    }
}

// ---------------------------------------------------------------------------
// Fused attention, SINGLE-SWEEP with LDS exp-cache.
// Block = (b, 32 k-cols) x all 2048 q, 1024 threads = 16 waves, 1 block/CU
// (dynamic LDS: 136 B/lane exp-cache = 139 KB + 2.2 KB static).
// R4-R6 lesson: the compiler refuses to keep a register exp-cache live
// across the barrier (spills to scratch at any spelling) -> cache in LDS,
// where the allocator has no say.
// Phase A: sweep q once: MFMA -> exp2 (the only TRANS pass) -> colsum l;
//          pack exp as f16 pairs, ds_write_b64 to the per-lane region.
// Phase B: ds_read_b64 + FMA + 16-lane reduce + one atomicAdd per row.
//          No Q loads, no MFMA, no exp2 in phase B.
// Grid swizzle: all 64 k-blocks of one batch land on one XCD -> per-XCD L2
// working set ~0.5 MB (Q of 2 batches) instead of ~4 MB (thrash).
// ---------------------------------------------------------------------------
__global__ __launch_bounds__(1024) void k_attn(
    const ushort* __restrict__ Qb, const ushort* __restrict__ Kb,
    const float* __restrict__ vf, const float* __restrict__ bfp,
    float* __restrict__ outp)
{
    // bijective XCD swizzle: 1024 blocks, 128 consecutive work-items per XCD
    const int bid = blockIdx.x;
    const int sw  = (bid & 7) * (NKBLK * BATCH / 8) + (bid >> 3);
    const int b   = sw >> 6;            // 64 k-blocks per batch
    const int k0  = (sw & 63) * KCOLS;

    const int tid  = threadIdx.x;
    const int wave = tid >> 6;
    const int lane = tid & 63;
    const int quad = lane >> 4;
    const int col  = lane & 15;

    extern __shared__ char smem[];      // exp cache, 136 B per thread
    uint2* cache = (uint2*)(smem + tid * CACHE_STRIDE);
    __shared__ float sl[16][KCOLS];
    __shared__ float wcol[KCOLS];

    // resident K fragments: 2 tiles x 2 chunks (32 k-cols)
    bf16x8 kf[2][2];
    {
        const ushort* Kbase = Kb + ((size_t)(b * SEQ + k0)) * DIM;
        #pragma unroll
        for (int t = 0; t < 2; ++t)
            #pragma unroll
            for (int c = 0; c < 2; ++c)
                kf[t][c] = *(const bf16x8*)(Kbase + (size_t)(t * 16 + col) * DIM + quad * 8 + c * 32);
    }

    const ushort* Qstart = Qb + ((size_t)(b * SEQ + wave * 128 + col)) * DIM + quad * 8;

    // ---- Phase A: single sweep: colsum + f16 exp-cache in LDS ----
    float l[2] = {0.f, 0.f};
    #pragma unroll
    for (int qi = 0; qi < 8; ++qi) {
        const ushort* Qtile = Qstart + qi * 16 * DIM;
        bf16x8 a0 = *(const bf16x8*)(Qtile);
        bf16x8 a1 = *(const bf16x8*)(Qtile + 32);
        #pragma unroll
        for (int t = 0; t < 2; ++t) {
            f32x4 acc = {0.f, 0.f, 0.f, 0.f};
            acc = __builtin_amdgcn_mfma_f32_16x16x32_bf16(a0, kf[t][0], acc, 0, 0, 0);
            acc = __builtin_amdgcn_mfma_f32_16x16x32_bf16(a1, kf[t][1], acc, 0, 0, 0);
            float e0 = fast_exp2(acc.x), e1 = fast_exp2(acc.y);
            float e2 = fast_exp2(acc.z), e3 = fast_exp2(acc.w);
            l[t] += (e0 + e1) + (e2 + e3);
            cache[qi * 2 + t] = make_uint2(packf16(e0, e1), packf16(e2, e3));
        }
    }
    #pragma unroll
    for (int t = 0; t < 2; ++t) {
        l[t] += __shfl_xor(l[t], 16);
        l[t] += __shfl_xor(l[t], 32);
    }
    if (quad == 0) {
        sl[wave][col]      = l[0];
        sl[wave][16 + col] = l[1];
    }
    __syncthreads();
    if (tid < KCOLS) {
        float ll = 0.f;
        #pragma unroll
        for (int w = 0; w < 16; ++w) ll += sl[w][tid];
        wcol[tid] = vf[(size_t)b * SEQ + k0 + tid] / ll;
    }
    __syncthreads();

    // ---- Phase B: LDS cache sweep -> atomic accumulate ----
    const float bias = bfp[0] * (1.0f / NKBLK);   // each k-block adds bf/64
    float wreg[2];
    wreg[0] = wcol[col];
    wreg[1] = wcol[16 + col];
    float* outb = outp + (size_t)b * SEQ;

    #pragma unroll
    for (int qi = 0; qi < 8; ++qi) {
        float rs[4] = {0.f, 0.f, 0.f, 0.f};
        #pragma unroll
        for (int t = 0; t < 2; ++t) {
            uint2 pk = cache[qi * 2 + t];
            float2 e01 = unpackf16(pk.x);
            float2 e23 = unpackf16(pk.y);
            rs[0] += e01.x * wreg[t];
            rs[1] += e01.y * wreg[t];
            rs[2] += e23.x * wreg[t];
            rs[3] += e23.y * wreg[t];
        }
        // reduce over the 16 k-cols (low 4 lane bits)
        #pragma unroll
        for (int r = 0; r < 4; ++r) {
            float v = rs[r];
            v += __shfl_xor(v, 1); v += __shfl_xor(v, 2);
            v += __shfl_xor(v, 4); v += __shfl_xor(v, 8);
            rs[r] = v;
        }
        if (col == 0) {
            const int qrow = wave * 128 + qi * 16 + quad * 4;
            #pragma unroll
            for (int r = 0; r < 4; ++r)
                atomicAdd(&outb[qrow + r], rs[r] + bias);
        }
    }
}

// ---------------------------------------------------------------------------
extern "C" void kernel_launch(void* const* d_in, const int* in_sizes, int n_in,
                              void* d_out, int out_size, void* d_ws, size_t ws_size,
                              hipStream_t stream) {
    (void)in_sizes; (void)n_in; (void)ws_size;
    const float* x  = (const float*)d_in[0];
    const float* Wq = (const float*)d_in[1];
    const float* Wk = (const float*)d_in[2];
    const float* Wv = (const float*)d_in[3];
    const float* Wf = (const float*)d_in[4];
    const float* bf = (const float*)d_in[5];
    float* outp = (float*)d_out;

    float*  wvf = (float*)d_ws;                                  // 256 floats
    float*  vf  = wvf + 256;                                     // B*S
    float*  pe  = vf + (size_t)BATCH * SEQ;                      // S*H f32 (1 MB)
    ushort* Wt  = (ushort*)(pe + (size_t)SEQ * HID);             // 128*128
    ushort* Qb  = Wt + 128 * 128;                                // B*S*D bf16
    ushort* Kb  = Qb + (size_t)BATCH * SEQ * DIM;                // B*S*D bf16

    static bool attr_set = false;
    if (!attr_set) {
        hipFuncSetAttribute((const void*)k_attn,
                            hipFuncAttributeMaxDynamicSharedMemorySize,
                            CACHE_BYTES);
        attr_set = true;
    }

    hipMemsetAsync(d_out, 0, (size_t)out_size * sizeof(float), stream);
    k_prep<<<SEQ * HID / 256, 256, 0, stream>>>(Wq, Wk, Wv, Wf, Wt, wvf, pe);
    k_qkv<<<BATCH * SEQ / 64, 256, 0, stream>>>(x, Wt, wvf, pe, Qb, Kb, vf);
    k_attn<<<NKBLK * BATCH, 1024, CACHE_BYTES, stream>>>(Qb, Kb, vf, bf, outp);
}

// Round 8
// 138.775 us; speedup vs baseline: 1.3907x; 1.3907x over previous
//
#include <hip/hip_runtime.h>
#include <hip/hip_bf16.h>
#include <math.h>

#define BATCH 16
#define SEQ   2048
#define HID   128
#define DIM   64
#define NKBLK (SEQ / 64)              // 32 k-blocks (of 64 cols) per batch

typedef __attribute__((ext_vector_type(8))) short bf16x8;
typedef __attribute__((ext_vector_type(4))) float f32x4;

// 0.125 (1/sqrt(D)) * log2(e): folded into Wq so MFMA emits log2-domain scores
#define QSCALE 0.18033688011112042f
#define C0_PE  0.07195578314043169f   // ln(10000)/128

static __device__ __forceinline__ ushort f2bf(float f) {
    __hip_bfloat16 h = __float2bfloat16(f);
    return *reinterpret_cast<ushort*>(&h);
}

static __device__ __forceinline__ float fast_exp2(float x) {
#if __has_builtin(__builtin_amdgcn_exp2f)
    return __builtin_amdgcn_exp2f(x);
#else
    return exp2f(x);
#endif
}

// ---------------------------------------------------------------------------
// Prep (1024 blocks): wvf[h] = Wv[h,:]·Wf ;  Wt = bf16 [Wq*QSCALE | Wk]^T ;
// pe[s][h] = sinusoidal PE table (f32, 1 MB).
// ---------------------------------------------------------------------------
__global__ __launch_bounds__(256) void k_prep(
    const float* __restrict__ Wq, const float* __restrict__ Wk,
    const float* __restrict__ Wv, const float* __restrict__ Wf,
    ushort* __restrict__ Wt, float* __restrict__ wvf, float* __restrict__ pe) {
    const int gid = blockIdx.x * 256 + threadIdx.x;
    if (gid < HID) {
        float s = 0.f;
        #pragma unroll 8
        for (int d = 0; d < DIM; ++d) s += Wv[gid * DIM + d] * Wf[d];
        wvf[gid] = s;
    }
    if (gid < 128 * 128) {
        int col = gid >> 7, k = gid & 127;
        float v = (col < 64) ? Wq[k * DIM + col] * QSCALE : Wk[k * DIM + (col - 64)];
        Wt[gid] = f2bf(v);
    }
    {
        int s = gid >> 7, h = gid & 127;
        int he = h & ~1;
        float ang = (float)s * __expf(-(float)he * C0_PE);
        pe[gid] = (h & 1) ? __cosf(ang) : __sinf(ang);
    }
}

// ---------------------------------------------------------------------------
// QKV (MFMA, no LDS): block = 64 rows, wave = 16 rows.
// ---------------------------------------------------------------------------
__global__ __launch_bounds__(256) void k_qkv(
    const float* __restrict__ x, const ushort* __restrict__ Wt,
    const float* __restrict__ wvf, const float* __restrict__ pe,
    ushort* __restrict__ Qb, ushort* __restrict__ Kb, float* __restrict__ vf)
{
    const int tid  = threadIdx.x;
    const int wave = tid >> 6;
    const int lane = tid & 63;
    const int quad = lane >> 4;
    const int col  = lane & 15;
    const int rowbase = blockIdx.x * 64 + wave * 16;
    const int grow = rowbase + col;
    const int srow = grow & (SEQ - 1);

    bf16x8 af[4];
    float vpart = 0.f;
    #pragma unroll
    for (int c = 0; c < 4; ++c) {
        const float* xp = x + (size_t)grow * HID + quad * 8 + c * 32;
        float4 v0 = *(const float4*)(xp);
        float4 v1 = *(const float4*)(xp + 4);
        const float* per = pe + (size_t)srow * HID + quad * 8 + c * 32;
        float4 p0 = *(const float4*)(per);
        float4 p1 = *(const float4*)(per + 4);
        float t[8] = {v0.x + p0.x, v0.y + p0.y, v0.z + p0.z, v0.w + p0.w,
                      v1.x + p1.x, v1.y + p1.y, v1.z + p1.z, v1.w + p1.w};
        const float* wp = wvf + quad * 8 + c * 32;
        float4 w0 = *(const float4*)(wp);
        float4 w1 = *(const float4*)(wp + 4);
        vpart += t[0] * w0.x + t[1] * w0.y + t[2] * w0.z + t[3] * w0.w +
                 t[4] * w1.x + t[5] * w1.y + t[6] * w1.z + t[7] * w1.w;
        short* ap = (short*)&af[c];
        #pragma unroll
        for (int j = 0; j < 8; ++j) ap[j] = (short)f2bf(t[j]);
    }

    vpart += __shfl_xor(vpart, 16);
    vpart += __shfl_xor(vpart, 32);
    if (quad == 0) vf[grow] = vpart;

    #pragma unroll
    for (int t = 0; t < 8; ++t) {
        const ushort* wrow = Wt + (size_t)(t * 16 + col) * 128 + quad * 8;
        f32x4 acc = {0.f, 0.f, 0.f, 0.f};
        #pragma unroll
        for (int c = 0; c < 4; ++c) {
            bf16x8 bfr = *(const bf16x8*)(wrow + c * 32);
            acc = __builtin_amdgcn_mfma_f32_16x16x32_bf16(af[c], bfr, acc, 0, 0, 0);
        }
        const int cb = (t & 3) * 16 + col;
        ushort* dst = (t < 4) ? Qb : Kb;
        const int r0 = rowbase + quad * 4;
        #pragma unroll
        for (int r = 0; r < 4; ++r)
            dst[(size_t)(r0 + r) * DIM + cb] = f2bf(acc[r]);
    }
}

// ---------------------------------------------------------------------------
// Fused attention (R2-exact structure, 48.1 µs baseline): block = (b, 64
// k-cols), 1024 threads = 16 waves, LDS 4.6 KB -> 2 resident blocks/CU
// (R7 proved 1-resident-block serializes barrier/tail drains: 109 µs).
// ONE change vs R2: 1D grid + bijective XCD swizzle so each XCD owns 2
// complete batches -> per-XCD L2 Q working set 512 KB (vs ~4 MB thrash
// with default round-robin) -> Q-stream loads become L2 hits, attacking
// the load->MFMA->exp2 dependent-chain stall that TLP couldn't hide.
// ---------------------------------------------------------------------------
__global__ __launch_bounds__(1024) void k_attn(
    const ushort* __restrict__ Qb, const ushort* __restrict__ Kb,
    const float* __restrict__ vf, const float* __restrict__ bfp,
    float* __restrict__ outp)
{
    // bijective XCD swizzle: 512 blocks, XCD = bid%8 owns 64 consecutive
    // work items = 2 complete batches (b = sw>>5).
    const int bid = blockIdx.x;
    const int sw  = (bid & 7) * (NKBLK * BATCH / 8) + (bid >> 3);
    const int b   = sw >> 5;            // 32 k-blocks per batch
    const int k0  = (sw & 31) * 64;

    const int tid  = threadIdx.x;
    const int wave = tid >> 6;
    const int lane = tid & 63;
    const int quad = lane >> 4;
    const int col  = lane & 15;

    __shared__ float sl[16][64];
    __shared__ float wcol[64];

    // resident K fragments: 4 tiles x 2 chunks
    bf16x8 kf[4][2];
    {
        const ushort* Kbase = Kb + ((size_t)(b * SEQ + k0)) * DIM;
        #pragma unroll
        for (int t = 0; t < 4; ++t)
            #pragma unroll
            for (int c = 0; c < 2; ++c)
                kf[t][c] = *(const bf16x8*)(Kbase + (size_t)(t * 16 + col) * DIM + quad * 8 + c * 32);
    }

    const ushort* Qstart = Qb + ((size_t)(b * SEQ + wave * 128 + col)) * DIM + quad * 8;

    // ---- Phase A: column sums (each wave: 128 q rows = 8 tiles of 16) ----
    float l[4] = {0.f, 0.f, 0.f, 0.f};
    {
        const ushort* Qrow = Qstart;
        for (int qi = 0; qi < 8; ++qi) {
            bf16x8 a0 = *(const bf16x8*)(Qrow);
            bf16x8 a1 = *(const bf16x8*)(Qrow + 32);
            Qrow += 16 * DIM;
            #pragma unroll
            for (int t = 0; t < 4; ++t) {
                f32x4 acc = {0.f, 0.f, 0.f, 0.f};
                acc = __builtin_amdgcn_mfma_f32_16x16x32_bf16(a0, kf[t][0], acc, 0, 0, 0);
                acc = __builtin_amdgcn_mfma_f32_16x16x32_bf16(a1, kf[t][1], acc, 0, 0, 0);
                l[t] += fast_exp2(acc.x) + fast_exp2(acc.y) +
                        fast_exp2(acc.z) + fast_exp2(acc.w);
            }
        }
    }
    #pragma unroll
    for (int t = 0; t < 4; ++t) {
        l[t] += __shfl_xor(l[t], 16);
        l[t] += __shfl_xor(l[t], 32);
    }
    if (quad == 0) {
        #pragma unroll
        for (int t = 0; t < 4; ++t) sl[wave][t * 16 + col] = l[t];
    }
    __syncthreads();
    if (tid < 64) {
        float ll = 0.f;
        #pragma unroll
        for (int w = 0; w < 16; ++w) ll += sl[w][tid];
        wcol[tid] = vf[(size_t)b * SEQ + k0 + tid] / ll;
    }
    __syncthreads();

    // ---- Phase B: weighted row sums -> atomic accumulate ----
    const float bias = bfp[0] * (1.0f / NKBLK);   // each block adds bf/32
    float wreg[4];
    #pragma unroll
    for (int t = 0; t < 4; ++t) wreg[t] = wcol[t * 16 + col];

    {
        const ushort* Qrow = Qstart;
        float* outb = outp + (size_t)b * SEQ;
        for (int qi = 0; qi < 8; ++qi) {
            bf16x8 a0 = *(const bf16x8*)(Qrow);
            bf16x8 a1 = *(const bf16x8*)(Qrow + 32);
            Qrow += 16 * DIM;
            float rs[4] = {0.f, 0.f, 0.f, 0.f};
            #pragma unroll
            for (int t = 0; t < 4; ++t) {
                f32x4 acc = {0.f, 0.f, 0.f, 0.f};
                acc = __builtin_amdgcn_mfma_f32_16x16x32_bf16(a0, kf[t][0], acc, 0, 0, 0);
                acc = __builtin_amdgcn_mfma_f32_16x16x32_bf16(a1, kf[t][1], acc, 0, 0, 0);
                #pragma unroll
                for (int r = 0; r < 4; ++r)
                    rs[r] += fast_exp2(acc[r]) * wreg[t];
            }
            // reduce over the 16 k-cols (low 4 lane bits)
            #pragma unroll
            for (int r = 0; r < 4; ++r) {
                float v = rs[r];
                v += __shfl_xor(v, 1); v += __shfl_xor(v, 2);
                v += __shfl_xor(v, 4); v += __shfl_xor(v, 8);
                rs[r] = v;
            }
            if (col == 0) {
                const int qrow = wave * 128 + qi * 16 + quad * 4;
                #pragma unroll
                for (int r = 0; r < 4; ++r)
                    atomicAdd(&outb[qrow + r], rs[r] + bias);
            }
        }
    }
}

// ---------------------------------------------------------------------------
extern "C" void kernel_launch(void* const* d_in, const int* in_sizes, int n_in,
                              void* d_out, int out_size, void* d_ws, size_t ws_size,
                              hipStream_t stream) {
    (void)in_sizes; (void)n_in; (void)ws_size;
    const float* x  = (const float*)d_in[0];
    const float* Wq = (const float*)d_in[1];
    const float* Wk = (const float*)d_in[2];
    const float* Wv = (const float*)d_in[3];
    const float* Wf = (const float*)d_in[4];
    const float* bf = (const float*)d_in[5];
    float* outp = (float*)d_out;

    float*  wvf = (float*)d_ws;                                  // 256 floats
    float*  vf  = wvf + 256;                                     // B*S
    float*  pe  = vf + (size_t)BATCH * SEQ;                      // S*H f32 (1 MB)
    ushort* Wt  = (ushort*)(pe + (size_t)SEQ * HID);             // 128*128
    ushort* Qb  = Wt + 128 * 128;                                // B*S*D bf16
    ushort* Kb  = Qb + (size_t)BATCH * SEQ * DIM;                // B*S*D bf16

    hipMemsetAsync(d_out, 0, (size_t)out_size * sizeof(float), stream);
    k_prep<<<SEQ * HID / 256, 256, 0, stream>>>(Wq, Wk, Wv, Wf, Wt, wvf, pe);
    k_qkv<<<BATCH * SEQ / 64, 256, 0, stream>>>(x, Wt, wvf, pe, Qb, Kb, vf);
    k_attn<<<NKBLK * BATCH, 1024, 0, stream>>>(Qb, Kb, vf, bf, outp);
}